// Round 5
// baseline (228.405 us; speedup 1.0000x reference)
//
#include <hip/hip_runtime.h>
#include <hip/hip_fp16.h>
#include <math.h>

#define POUT 7
#define NCH 256

typedef float v4f __attribute__((ext_vector_type(4)));

// ---------------- level geometry (elements == half-elements of ws) ----------
#define HW0 40000
#define HW1 10000
#define HW2 2500
#define HW3 625
#define WS_OFF0 0
#define WS_OFF1 (2*NCH*HW0)
#define WS_OFF2 (WS_OFF1 + 2*NCH*HW1)
#define WS_OFF3 (WS_OFF2 + 2*NCH*HW2)
#define WS_ELEMS (WS_OFF3 + 2*NCH*HW3)      // 27,200,000 halves = 54.4 MB
// +512 halves slack (zeroed by transpose block 0): the unconditional +NCH
// tap read may touch <=256 halves past the last image (weight exactly 0).
#define WS_SLACK 512
#define WS_PERM_BYTE ((size_t)(WS_ELEMS + WS_SLACK) * 2)
#define WS_NEED (WS_PERM_BYTE + 1024 * sizeof(int))

// ---------------- fused NCHW(f32) -> NHWC(fp16) transpose, all 4 levels -----
// 56 pos x 128 ch tiles, 512 thr, LDS 29.2 KB. ch-half fastest block axis so
// sibling blocks write complementary 256 B chunks of the same position row.
// Reads are PLAIN CACHED (r3 evidence: FETCH 76 MB < 109 MB input -> L3 serves
// re-reads across iterations; r4's nontemporal loads defeated that).
// Block 0 additionally zeroes the ws slack and bitonic-sorts boxes by
// (img,lvl,y,x) -> perm (n | l<<10 | img<<12) for gather L2 locality.
#define TP 56
#define RS 114
#define NT0 ((HW0 + TP - 1) / TP)   // 715
#define NT1 ((HW1 + TP - 1) / TP)   // 179
#define NT2 ((HW2 + TP - 1) / TP)   // 45
#define NT3 ((HW3 + TP - 1) / TP)   // 12
#define NBLK ((NT0 + NT1 + NT2 + NT3) * 4)   // 3804

__global__ __launch_bounds__(512, 8) void transpose_fused_kernel(
    const float* __restrict__ f0, const float* __restrict__ f1,
    const float* __restrict__ f2, const float* __restrict__ f3,
    __half* __restrict__ ws, const float* __restrict__ props,
    int boxes_per_img, int N)
{
    __shared__ float tile[64 * RS];   // 29,184 B

    const int gid = blockIdx.x;
    int id = gid;
    const float* src; int HW, nt; size_t woff;
    if (id < NT0 * 4)                        { src = f0; HW = HW0; nt = NT0; woff = WS_OFF0; }
    else if ((id -= NT0 * 4) < NT1 * 4)      { src = f1; HW = HW1; nt = NT1; woff = WS_OFF1; }
    else if ((id -= NT1 * 4) < NT2 * 4)      { src = f2; HW = HW2; nt = NT2; woff = WS_OFF2; }
    else { id -= NT2 * 4;                      src = f3; HW = HW3; nt = NT3; woff = WS_OFF3; }

    const int ch = id & 1;                  // fastest: complementary row halves
    const int tl = (id >> 1) % nt;
    const int bb = (id >> 1) / nt;
    const int p0 = tl * TP;
    const int pn = min(TP, HW - p0);
    const int c0 = ch * 128;
    const int t  = threadIdx.x;

    const float* sbase = src + ((size_t)(bb * NCH + c0)) * HW + p0;

    // ---- in: 128 channel-rows x 14 float4 (224 B contiguous, cached) ----
    if (pn == TP) {
        for (int i = t; i < 128 * (TP / 4); i += 512) {
            const int c  = i / (TP / 4);
            const int p4 = i - c * (TP / 4);
            const float4 v = *(const float4*)&sbase[(size_t)c * HW + p4 * 4];
            float* d = &tile[(c >> 1) * RS + (c & 1) + p4 * 8];
            d[0] = v.x; d[2] = v.y; d[4] = v.z; d[6] = v.w;
        }
    } else {
        for (int i = t; i < 128 * (TP / 4); i += 512) {
            const int c  = i / (TP / 4);
            const int pb = (i - c * (TP / 4)) * 4;
            float vv[4];
            #pragma unroll
            for (int k = 0; k < 4; ++k)
                vv[k] = (pb + k < pn) ? sbase[(size_t)c * HW + pb + k] : 0.0f;
            float* d = &tile[(c >> 1) * RS + (c & 1) + pb * 2];
            d[0] = vv[0]; d[2] = vv[1]; d[4] = vv[2]; d[6] = vv[3];
        }
    }
    __syncthreads();

    // ---- out: half4 (uint2) per lane; wave = 2 position rows x 256 B ----
    __half* dbase = ws + woff + ((size_t)bb * HW + p0) * NCH + c0;
    for (int i = t; i < 32 * TP; i += 512) {
        const int u2 = i & 31, p = i >> 5;
        if (p < pn) {
            // row r holds channels 2r,2r+1 at cols 2p,2p+1
            const float2 a = *(const float2*)&tile[(2 * u2    ) * RS + 2 * p];
            const float2 c2v = *(const float2*)&tile[(2 * u2 + 1) * RS + 2 * p];
            const __half2 h0 = __floats2half2_rn(a.x, a.y);     // ch 4u2,4u2+1
            const __half2 h1 = __floats2half2_rn(c2v.x, c2v.y); // ch 4u2+2,4u2+3
            uint2 w;
            w.x = *reinterpret_cast<const unsigned*>(&h0);
            w.y = *reinterpret_cast<const unsigned*>(&h1);
            *(uint2*)&dbase[(size_t)p * NCH + 4 * u2] = w;
        }
    }

    // ---- block 0: zero slack + bitonic sort (hidden under other blocks) ----
    if (gid == 0) {
        __syncthreads();
        unsigned* keys = (unsigned*)tile;
        if (N == 1024) {
            for (int i = t; i < 1024; i += 512) {
                const float4 box = ((const float4*)props)[i];
                const float area = (box.z - box.x) * (box.w - box.y);
                float lvlf = floorf(4.0f + log2f(sqrtf(area) / 224.0f + 1e-6f));
                lvlf = fminf(fmaxf(lvlf, 2.0f), 5.0f) - 2.0f;
                const int l = (int)lvlf;
                const float sc = 0.25f / (float)(1 << l);
                int yc = (int)(0.5f * (box.y + box.w) * sc);
                int xc = (int)(0.5f * (box.x + box.z) * sc);
                yc = yc < 0 ? 0 : (yc > 255 ? 255 : yc);
                xc = xc < 0 ? 0 : (xc > 255 ? 255 : xc);
                const unsigned hi = (unsigned)((i / boxes_per_img) * 4 + l);
                keys[i] = (((hi << 8 | (unsigned)yc) << 8 | (unsigned)xc) << 10) | (unsigned)i;
            }
            for (int size = 2; size <= 1024; size <<= 1)
                for (int stride = size >> 1; stride > 0; stride >>= 1) {
                    __syncthreads();
                    const int lo = t & (stride - 1);
                    const int k  = ((t ^ lo) << 1) | lo;
                    const unsigned a = keys[k], b2 = keys[k + stride];
                    if ((a > b2) == ((k & size) == 0)) { keys[k] = b2; keys[k + stride] = a; }
                }
            __syncthreads();
            int* perm = (int*)((char*)ws + WS_PERM_BYTE);
            for (int i = t; i < 1024; i += 512) {
                const unsigned k = keys[i];
                perm[i] = (int)((k & 1023u) | (((k >> 26) & 3u) << 10) | ((k >> 28) << 12));
            }
        }
        if (t < 256) ((unsigned*)(ws + WS_ELEMS))[t] = 0u;   // 512 halves
    }
}

// ---------------- 196-sample gather from fp16 NHWC, f32 weights -------------
// Thread = (channel-quad c4 = t&63, bin-quarter qt = t>>6). Each tap load is
// half4 (8 B/lane; wave = 512 B contiguous). Quarters partition the 49 bins
// 13/12/12/12. Output staged via LDS, stored as nt float4.
__global__ __launch_bounds__(256, 4) void roi_gather_kernel(
    const __half* __restrict__ ws, const float* __restrict__ props,
    float* __restrict__ out, int boxes_per_img)
{
    __shared__ int2   sOff[196];
    __shared__ float4 sW[196];
    __shared__ __align__(16) float sStage[64 * 49];

    const int* perm = (const int*)((const char*)ws + WS_PERM_BYTE);
    const int pe = perm[(blockIdx.x & 7) * 128 + (blockIdx.x >> 3)];
    const int n = pe & 1023;
    const int l = (pe >> 10) & 3;
    const int b = pe >> 12;
    const int t = threadIdx.x;

    int sz; size_t lvl_off;
    if      (l == 0) { sz = 200; lvl_off = WS_OFF0; }
    else if (l == 1) { sz = 100; lvl_off = WS_OFF1; }
    else if (l == 2) { sz = 50;  lvl_off = WS_OFF2; }
    else             { sz = 25;  lvl_off = WS_OFF3; }
    const int HW = sz * sz;
    const float scale = 0.25f / (float)(1 << l);

    if (t < 196) {
        const float4 box = ((const float4*)props)[n];
        const int bin = t >> 2, sub = t & 3;
        const int ph = bin / POUT, pw = bin % POUT;
        const int iy = sub >> 1,  ix = sub & 1;

        const float x0 = box.x * scale, y0 = box.y * scale;
        const float x1 = box.z * scale, y1 = box.w * scale;
        const float bin_w = fmaxf(x1 - x0, 1.0f) / (float)POUT;
        const float bin_h = fmaxf(y1 - y0, 1.0f) / (float)POUT;

        const float ys = y0 + ((float)ph + ((float)iy + 0.5f) * 0.5f) * bin_h;
        const float xs = x0 + ((float)pw + ((float)ix + 0.5f) * 0.5f) * bin_w;

        const bool  vy  = (ys >= -1.0f) && (ys <= (float)sz);
        const float cy  = fmaxf(ys, 0.0f);
        const int   yl0 = (int)floorf(cy);
        const bool  ey  = yl0 >= sz - 1;
        const int   yl  = ey ? sz - 1 : yl0;
        const int   yh  = ey ? sz - 1 : yl0 + 1;
        const float ly  = ey ? 0.0f : cy - (float)yl0;

        const bool  vx  = (xs >= -1.0f) && (xs <= (float)sz);
        const float cx  = fmaxf(xs, 0.0f);
        const int   xl0 = (int)floorf(cx);
        const bool  ex  = xl0 >= sz - 1;
        const int   xl  = ex ? sz - 1 : xl0;
        const float lx  = ex ? 0.0f : cx - (float)xl0;

        const float hy = 1.0f - ly, hx = 1.0f - lx;
        const float m  = (vy && vx) ? 0.25f : 0.0f;   // fold subsample mean
        sOff[t] = make_int2((yl * sz + xl) * NCH, (yh * sz + xl) * NCH);
        sW[t]   = make_float4(hy * hx * m, hy * lx * m, ly * hx * m, ly * lx * m);
    }
    __syncthreads();

    const int c4 = t & 63;               // channels 4c4..4c4+3
    const int qt = t >> 6;               // bin quarter
    const int bstart = (qt == 0) ? 0 : 13 + 12 * (qt - 1);   // 0,13,25,37
    const int bcnt   = (qt == 0) ? 13 : 12;
    const __half* fb = ws + lvl_off + (size_t)b * (size_t)HW * NCH + 4 * c4;

    float acc[13][4];
    #pragma unroll
    for (int j = 0; j < 13; ++j)
        #pragma unroll
        for (int k = 0; k < 4; ++k) acc[j][k] = 0.0f;

    #pragma unroll
    for (int j = 0; j < 13; ++j) {
        const int bin = min(bstart + j, 48);   // clamped dummy for tail lanes
        #pragma unroll
        for (int s = 0; s < 4; ++s) {
            const int2   o = sOff[bin * 4 + s];
            const float4 w = sW[bin * 4 + s];
            const uint2 r00 = *(const uint2*)&fb[o.x];
            const uint2 r01 = *(const uint2*)&fb[o.x + NCH];
            const uint2 r10 = *(const uint2*)&fb[o.y];
            const uint2 r11 = *(const uint2*)&fb[o.y + NCH];
            const float2 a00 = __half22float2(*(const __half2*)&r00.x);
            const float2 b00 = __half22float2(*(const __half2*)&r00.y);
            const float2 a01 = __half22float2(*(const __half2*)&r01.x);
            const float2 b01 = __half22float2(*(const __half2*)&r01.y);
            const float2 a10 = __half22float2(*(const __half2*)&r10.x);
            const float2 b10 = __half22float2(*(const __half2*)&r10.y);
            const float2 a11 = __half22float2(*(const __half2*)&r11.x);
            const float2 b11 = __half22float2(*(const __half2*)&r11.y);
            acc[j][0] += w.x * a00.x + w.y * a01.x + w.z * a10.x + w.w * a11.x;
            acc[j][1] += w.x * a00.y + w.y * a01.y + w.z * a10.y + w.w * a11.y;
            acc[j][2] += w.x * b00.x + w.y * b01.x + w.z * b10.x + w.w * b11.x;
            acc[j][3] += w.x * b00.y + w.y * b01.y + w.z * b10.y + w.w * b11.y;
        }
    }

    // ---- staged stores: 64 channels x 49 bins per round, nt float4 ----
    __syncthreads();
    float* obase = out + (size_t)n * (NCH * 49);
    #pragma unroll
    for (int r = 0; r < 4; ++r) {
        if ((c4 >> 4) == r) {
            const int lc = (c4 & 15) * 4;
            for (int j = 0; j < bcnt; ++j)
                #pragma unroll
                for (int k = 0; k < 4; ++k)
                    sStage[(lc + k) * 49 + bstart + j] = acc[j][k];
        }
        __syncthreads();
        v4f* d4 = (v4f*)(obase + r * (64 * 49));
        const v4f* s4 = (const v4f*)sStage;
        for (int i = t; i < 64 * 49 / 4; i += 256)
            __builtin_nontemporal_store(s4[i], &d4[i]);
        __syncthreads();
    }
}

// ---------------- fallback (general shapes, NCHW direct, f32) ---------------
__global__ __launch_bounds__(256, 4) void roi_align_nchw_kernel(
    const float* __restrict__ f0, const float* __restrict__ f1,
    const float* __restrict__ f2, const float* __restrict__ f3,
    const float* __restrict__ props, float* __restrict__ out, int boxes_per_img)
{
    const int n = blockIdx.x;
    const int t = threadIdx.x;
    if (t >= 196) return;
    const int bin = t >> 2, q = t & 3;
    const int ph = bin / POUT, pw = bin % POUT;
    const int iy = q >> 1,    ix = q & 1;
    const int b = n / boxes_per_img;

    const float4 box = ((const float4*)props)[n];
    const float area = (box.z - box.x) * (box.w - box.y);
    float lvlf = floorf(4.0f + log2f(sqrtf(area) / 224.0f + 1e-6f));
    lvlf = fminf(fmaxf(lvlf, 2.0f), 5.0f) - 2.0f;
    const int l = (int)lvlf;

    const float* feat; int sz;
    if      (l == 0) { feat = f0; sz = 200; }
    else if (l == 1) { feat = f1; sz = 100; }
    else if (l == 2) { feat = f2; sz = 50;  }
    else             { feat = f3; sz = 25;  }
    const float scale = 0.25f / (float)(1 << l);

    const float x0 = box.x * scale, y0 = box.y * scale;
    const float x1 = box.z * scale, y1 = box.w * scale;
    const float bin_w = fmaxf(x1 - x0, 1.0f) / (float)POUT;
    const float bin_h = fmaxf(y1 - y0, 1.0f) / (float)POUT;
    const float ysamp = y0 + ((float)ph + ((float)iy + 0.5f) * 0.5f) * bin_h;
    const float xsamp = x0 + ((float)pw + ((float)ix + 0.5f) * 0.5f) * bin_w;

    const bool  vy  = (ysamp >= -1.0f) && (ysamp <= (float)sz);
    const float cy  = fmaxf(ysamp, 0.0f);
    const int   yl0 = (int)floorf(cy);
    const bool  ey  = yl0 >= sz - 1;
    const int   yl  = ey ? sz - 1 : yl0;
    const int   yh  = ey ? sz - 1 : yl0 + 1;
    const float ly  = ey ? 0.0f : cy - (float)yl0;
    const bool  vx  = (xsamp >= -1.0f) && (xsamp <= (float)sz);
    const float cx  = fmaxf(xsamp, 0.0f);
    const int   xl0 = (int)floorf(cx);
    const bool  ex  = xl0 >= sz - 1;
    const int   xl  = ex ? sz - 1 : xl0;
    const int   xh  = ex ? sz - 1 : xl0 + 1;
    const float lx  = ex ? 0.0f : cx - (float)xl0;

    const float hy = 1.0f - ly, hx = 1.0f - lx;
    const float m  = (vy && vx) ? 1.0f : 0.0f;
    const float w00 = hy * hx * m, w01 = hy * lx * m;
    const float w10 = ly * hx * m, w11 = ly * lx * m;

    const int HW = sz * sz;
    const float* base = feat + (size_t)b * NCH * HW;
    int o00 = yl * sz + xl, o01 = yl * sz + xh;
    int o10 = yh * sz + xl, o11 = yh * sz + xh;
    float* op = out + (size_t)n * NCH * (POUT * POUT) + bin;

    #pragma unroll 4
    for (int cch = 0; cch < NCH; ++cch) {
        float v = w00 * base[o00] + w01 * base[o01]
                + w10 * base[o10] + w11 * base[o11];
        v += __shfl_xor(v, 1);
        v += __shfl_xor(v, 2);
        if (q == 0) op[cch * (POUT * POUT)] = v * 0.25f;
        o00 += HW; o01 += HW; o10 += HW; o11 += HW;
    }
}

extern "C" void kernel_launch(void* const* d_in, const int* in_sizes, int n_in,
                              void* d_out, int out_size, void* d_ws, size_t ws_size,
                              hipStream_t stream) {
    const float* f0 = (const float*)d_in[0];
    const float* f1 = (const float*)d_in[1];
    const float* f2 = (const float*)d_in[2];
    const float* f3 = (const float*)d_in[3];
    const float* props = (const float*)d_in[4];
    float* out = (float*)d_out;

    const int N = in_sizes[4] / 4;                 // 1024 boxes
    const int B = in_sizes[0] / (NCH * HW0);       // 2 images
    const int boxes_per_img = N / B;               // 512

    if (ws_size >= WS_NEED && B == 2 && N == 1024) {
        __half* wsh = (__half*)d_ws;
        transpose_fused_kernel<<<NBLK, 512, 0, stream>>>(f0, f1, f2, f3, wsh,
                                                         props, boxes_per_img, N);
        roi_gather_kernel<<<N, 256, 0, stream>>>(wsh, props, out, boxes_per_img);
    } else {
        roi_align_nchw_kernel<<<N, 256, 0, stream>>>(f0, f1, f2, f3, props, out, boxes_per_img);
    }
}